// Round 6
// baseline (237.541 us; speedup 1.0000x reference)
//
#include <hip/hip_runtime.h>

// ROIAlign (FPN multi-level) for MI355X — R6: MEASUREMENT ROUND.
// Kernel body identical to R5 (448-thread row-blocks, XCD swizzle).
// kernel_launch launches the kernel TWICE: dur_us(R6) - dur_us(R5) = true
// kernel device time K (top-5 rocprof is saturated by 80us harness memsets,
// making K invisible; dur_us decomposition has +-60us uncertainty in the
// 178MB input-restore term). Both launches write identical values ->
// deterministic, graph-capture safe.

#define B_SZ   2
#define N_ROI  512
#define CCH    256
#define OUT_S  7
#define NCELL  (OUT_S * OUT_S)

typedef float nfloat4 __attribute__((ext_vector_type(4)));

__global__ __launch_bounds__(448)
void roialign_kernel(const float* __restrict__ fm2,
                     const float* __restrict__ fm3,
                     const float* __restrict__ fm4,
                     const float* __restrict__ fm5,
                     const float* __restrict__ rois,
                     float* __restrict__ out)
{
    // decode swizzled block id -> (roi, row); wave id -> column
    const int bidx = blockIdx.x;
    const int g    = bidx & 7;            // XCD slot == roi & 7
    const int q    = bidx >> 3;           // 0 .. 895
    const int ihi  = q / OUT_S;           // 0 .. 127  (roi >> 3)
    const int jy   = q - ihi * OUT_S;     // row 0..6
    const int bn   = (ihi << 3) | g;      // ROI id 0..1023
    const int ix   = threadIdx.x >> 6;    // column 0..6 (wave id in block)
    const int b    = bn >> 9;             // batch (N=512)

    // ---- per-ROI setup (wave-uniform) ----
    const float4 roi = ((const float4*)rois)[bn];   // x1,y1,x2,y2
    const float x1 = roi.x, y1 = roi.y;
    const float w  = roi.z - roi.x;
    const float h  = roi.w - roi.y;

    float lvf = log2f(sqrtf(w * h) * (1.0f / 224.0f)) + 4.0f;
    int lv = (int)rintf(lvf);                   // RNE, matches jnp.round
    lv = min(max(lv, 2), 5) - 2;                // 0..3

    const float* fm = (lv == 0) ? fm2 : (lv == 1) ? fm3 : (lv == 2) ? fm4 : fm5;
    const int    H      = 256 >> lv;            // H == W
    const float  stride = (float)(4 << lv);
    const float  scale  = (float)(H - 1) / (stride * (float)H);

    // ---- sample coordinate for this (row, col) cell ----
    const float gy = (float)jy * (1.0f / 6.0f);
    const float gx = (float)ix * (1.0f / 6.0f);
    const float cy = (y1 + gy * h) * scale;     // ref: ((y1+g*h)/stride/H)*(H-1)
    const float cx = (x1 + gx * w) * scale;

    const int vld = (cy >= 0.0f) & (cy <= (float)(H - 1)) &
                    (cx >= 0.0f) & (cx <= (float)(H - 1));

    const float cyc = fminf(fmaxf(cy, 0.0f), (float)(H - 1));
    const float cxc = fminf(fmaxf(cx, 0.0f), (float)(H - 1));
    const int   y0  = (int)floorf(cyc);
    const int   x0  = (int)floorf(cxc);
    const float yl  = cyc - (float)y0;
    const float xl  = cxc - (float)x0;
    const int   y1i = min(y0 + 1, H - 1);
    const int   x1i = min(x0 + 1, H - 1);

    // ---- gather + bilinear: lane handles 4 channels (float4) ----
    const int c = (threadIdx.x & 63) * 4;

    const float* base = fm + (size_t)b * (size_t)H * (size_t)H * CCH;
    const float* rowT = base + (size_t)y0  * H * CCH;
    const float* rowB = base + (size_t)y1i * H * CCH;

    const float4 tl = *(const float4*)(rowT + x0  * CCH + c);
    const float4 tr = *(const float4*)(rowT + x1i * CCH + c);
    const float4 bl = *(const float4*)(rowB + x0  * CCH + c);
    const float4 br = *(const float4*)(rowB + x1i * CCH + c);

    nfloat4 o;
    {
        const float tx = tl.x + (tr.x - tl.x) * xl;
        const float bx = bl.x + (br.x - bl.x) * xl;
        o.x = tx + (bx - tx) * yl;
    }
    {
        const float ty = tl.y + (tr.y - tl.y) * xl;
        const float by = bl.y + (br.y - bl.y) * xl;
        o.y = ty + (by - ty) * yl;
    }
    {
        const float tz = tl.z + (tr.z - tl.z) * xl;
        const float bz = bl.z + (br.z - bl.z) * xl;
        o.z = tz + (bz - tz) * yl;
    }
    {
        const float tw = tl.w + (tr.w - tl.w) * xl;
        const float bw = bl.w + (br.w - bl.w) * xl;
        o.w = tw + (bw - tw) * yl;
    }
    if (!vld) { o.x = 0.0f; o.y = 0.0f; o.z = 0.0f; o.w = 0.0f; }

    // write-once output: non-temporal to keep it out of L2
    const int cell = jy * OUT_S + ix;
    nfloat4* dst = (nfloat4*)(out + (size_t)bn * NCELL * CCH + (size_t)cell * CCH + c);
    __builtin_nontemporal_store(o, dst);
}

extern "C" void kernel_launch(void* const* d_in, const int* in_sizes, int n_in,
                              void* d_out, int out_size, void* d_ws, size_t ws_size,
                              hipStream_t stream) {
    const float* fm2  = (const float*)d_in[0];
    const float* fm3  = (const float*)d_in[1];
    const float* fm4  = (const float*)d_in[2];
    const float* fm5  = (const float*)d_in[3];
    const float* rois = (const float*)d_in[4];
    float* out = (float*)d_out;

    dim3 grid(8 * (N_ROI * B_SZ / 8) * OUT_S);   // 7168 blocks (XCD-swizzled)
    dim3 block(64 * OUT_S);                      // 448 threads = 7 waves = 1 row

    // Launch TWICE (measurement: dur_us delta vs R5 == one kernel's device
    // time). Identical writes -> correctness unaffected.
    hipLaunchKernelGGL(roialign_kernel, grid, block, 0, stream,
                       fm2, fm3, fm4, fm5, rois, out);
    hipLaunchKernelGGL(roialign_kernel, grid, block, 0, stream,
                       fm2, fm3, fm4, fm5, rois, out);
}